// Round 14
// baseline (222.128 us; speedup 1.0000x reference)
//
#include <hip/hip_runtime.h>

using bf16x8 = __attribute__((ext_vector_type(8))) short;
using f32x4  = __attribute__((ext_vector_type(4))) float;
using f32x2  = __attribute__((ext_vector_type(2))) float;

constexpr int Bb = 8, Nn = 8192, Mm = 2048, C1 = 128, C2 = 256, Hh = 256, K1 = 384;
constexpr int KT1 = K1 / 32;   // 12 k-tiles for GEMM1
constexpr int KT2 = Hh / 32;   // 8 k-tiles for GEMM2
constexpr int RT = Hh / 16;    // 16 row-tiles
constexpr int NQ = 8;          // 8 segments (R11/R12)
constexpr int MQ = Mm / NQ;    // 256 candidates per segment

__device__ __forceinline__ short f2bf(float x) {  // RNE float->bf16
  union { float f; unsigned u; } v; v.f = x;
  unsigned r = v.u + 0x7fff + ((v.u >> 16) & 1);
  return (short)(r >> 16);
}

// packed RNE float2 -> 2x bf16 in one dword (hw instr when available)
__device__ __forceinline__ unsigned pk2bf(float a, float b) {
#if defined(__has_builtin) && __has_builtin(__builtin_amdgcn_cvt_pk_bf16_f32)
  typedef __attribute__((ext_vector_type(2))) __bf16 bf2_t;
  bf2_t r = __builtin_amdgcn_cvt_pk_bf16_f32(a, b);
  union { bf2_t v; unsigned u; } cvt; cvt.v = r;
  return cvt.u;
#else
  return (unsigned)(unsigned short)f2bf(a) | ((unsigned)(unsigned short)f2bf(b) << 16);
#endif
}

// unpack a dword holding 2 bf16 (lo = element 2i, hi = element 2i+1)
__device__ __forceinline__ float bflo(unsigned d) { return __uint_as_float(d << 16); }
__device__ __forceinline__ float bfhi(unsigned d) { return __uint_as_float(d & 0xffff0000u); }

// packed fp32. R13 lesson: v_pk_* fp32 appears throughput-neutral vs scalar
// (half-rate, 2 values/instr) — kept because it also halves the *instruction
// count* feeding the issue port, but no further gains expected from it.
__device__ __forceinline__ f32x2 pk_add(f32x2 a, f32x2 b) {
  f32x2 d; asm("v_pk_add_f32 %0, %1, %2" : "=v"(d) : "v"(a), "v"(b)); return d;
}
__device__ __forceinline__ f32x2 pk_mul(f32x2 a, f32x2 b) {
  f32x2 d; asm("v_pk_mul_f32 %0, %1, %2" : "=v"(d) : "v"(a), "v"(b)); return d;
}
__device__ __forceinline__ f32x2 pk_fma(f32x2 a, f32x2 b, f32x2 c) {
  f32x2 d; asm("v_pk_fma_f32 %0, %1, %2, %3" : "=v"(d) : "v"(a), "v"(b), "v"(c)); return d;
}

__device__ __forceinline__ float med3f(float a, float b, float c) {
#if defined(__has_builtin) && __has_builtin(__builtin_amdgcn_fmed3f)
  return __builtin_amdgcn_fmed3f(a, b, c);
#else
  return fmaxf(fminf(a, b), fminf(fmaxf(a, b), c));
#endif
}

// stable 2-list merge of sorted triples; ties prefer list a (lower global idx)
__device__ __forceinline__ void merge3(float a0, float a1, float a2, int A0, int A1, int A2,
                                       float b0, float b1, float b2, int B0, int B1, int B2,
                                       float& m0, float& m1, float& m2,
                                       int& j0, int& j1, int& j2) {
  bool ta = a0 <= b0;
  m0 = ta ? a0 : b0; j0 = ta ? A0 : B0;
  float na0 = ta ? a1 : a0, na1 = ta ? a2 : a1;
  int   nA0 = ta ? A1 : A0, nA1 = ta ? A2 : A1;
  float nb0 = ta ? b0 : b1, nb1 = ta ? b1 : b2;
  int   nB0 = ta ? B0 : B1, nB1 = ta ? B1 : B2;
  ta = na0 <= nb0;
  m1 = ta ? na0 : nb0; j1 = ta ? nA0 : nB0;
  float ma0 = ta ? na1 : na0; int mA0 = ta ? nA1 : nA0;
  float mb0 = ta ? nb0 : nb1; int mB0 = ta ? nB0 : nB1;
  ta = ma0 <= mb0;
  m2 = ta ? ma0 : mb0; j2 = ta ? mA0 : mB0;
}

// ------------- prep: kf transpose->bf16 (blocks 0..4095) + W frag prep -------------
// NOTE: prep, nn, fused stay SEPARATE kernels (R5/R6: fusing roles into one grid
// serialized the nn phase behind the transpose blocks, +40 us; launch overhead is
// fixed ~85 us regardless of kernel count — do not re-fuse).
__global__ __launch_bounds__(256) void prep_all_k(const float* __restrict__ kf,
                                                  short* __restrict__ kfTb,
                                                  const float* __restrict__ W1,
                                                  const float* __restrict__ W2,
                                                  short* __restrict__ W1f,
                                                  short* __restrict__ W2f) {
  __shared__ float tile[32][33];
  int bid = blockIdx.x, tid = threadIdx.x;
  if (bid < 4096) {  // transpose role: (B,C2,Mm) f32 -> (B,Mm,C2) bf16
    int cx = bid & 63, ry = (bid >> 6) & 7, z = bid >> 9;
    const float* src = kf + (size_t)z * C2 * Mm;
    short* dst = kfTb + (size_t)z * Mm * C2;
    int c0 = cx * 32, r0 = ry * 32;  // c0: point base, r0: channel base
    int tx = tid & 31, ty = tid >> 5;
#pragma unroll
    for (int rr = ty; rr < 32; rr += 8)
      tile[rr][tx] = src[(size_t)(r0 + rr) * Mm + c0 + tx];
    __syncthreads();
#pragma unroll
    for (int cc = ty; cc < 32; cc += 8)
      dst[(size_t)(c0 + cc) * C2 + r0 + tx] = f2bf(tile[tx][cc]);
    return;
  }
  // W-prep role: A-frag planes (lane holds A[m=lane&15][k0..k0+7], k0=(lane>>4)*8)
  int id = (bid - 4096) * 256 + tid;
  const int n1 = KT1 * RT * 64;
  const int n2 = KT2 * RT * 64;
  if (id < n1) {
    int lane = id & 63, t = id >> 6;
    int kt = t / RT, rt = t % RT;
    int m = rt * 16 + (lane & 15), k0 = kt * 32 + (lane >> 4) * 8;
    bf16x8 f;
#pragma unroll
    for (int j = 0; j < 8; ++j) f[j] = f2bf(W1[(size_t)m * K1 + k0 + j]);
    *(bf16x8*)(W1f + (size_t)id * 8) = f;
  } else if (id < n1 + n2) {
    int id2 = id - n1;
    int lane = id2 & 63, t = id2 >> 6;
    int kt = t / RT, rt = t % RT;
    int m = rt * 16 + (lane & 15), k0 = kt * 32 + (lane >> 4) * 8;
    bf16x8 f;
#pragma unroll
    for (int j = 0; j < 8; ++j) f[j] = f2bf(W2[(size_t)m * Hh + k0 + j]);
    *(bf16x8*)(W2f + (size_t)id2 * 8) = f;
  }
}

// ------------- three_nn: 2 queries/thread over 1/8 of the candidate set -------------
// grid: b(8) x nblk(16) x q(8) = 1024 blocks of 256 -> 4 waves/SIMD.
// R14: R13's instruction surgery was flat (VALUBusy 81% both ways — issue stream
// is ~30 slots/pair regardless of formulation). Remaining levers: the 19% stall
// and per-pair load overhead. Each thread now scans the SAME candidate stream
// for TWO queries: loads amortize x2, and the two independent insert chains
// interleave (ILP) to fill issue bubbles. Selection logic per query unchanged.
__global__ __launch_bounds__(256, 4) void nn_part_k(const float* __restrict__ unknown,
                                                    const float* __restrict__ known,
                                                    float* __restrict__ pd,
                                                    int* __restrict__ pi) {
  __shared__ float kx[MQ], ky[MQ], kz[MQ];
  int bid = blockIdx.x;
  int b = bid >> 7, rem = bid & 127;
  int q = rem & 7, nblk = rem >> 3;      // nblk 0..15
  int nA = nblk * 512 + threadIdx.x;     // query A
  int nB = nA + 256;                     // query B
  const float* kb = known + ((size_t)b * Mm + q * MQ) * 3;
  for (int p = threadIdx.x; p < MQ; p += 256) {
    kx[p] = kb[3 * p]; ky[p] = kb[3 * p + 1]; kz[p] = kb[3 * p + 2];
  }
  __syncthreads();

  size_t uiA = ((size_t)b * Nn + nA) * 3;
  size_t uiB = ((size_t)b * Nn + nB) * 3;
  float uxA = unknown[uiA], uyA = unknown[uiA + 1], uzA = unknown[uiA + 2];
  float uxB = unknown[uiB], uyB = unknown[uiB + 1], uzB = unknown[uiB + 2];
  float d0A = 1e30f, d1A = 1e30f, d2A = 1e30f;
  float d0B = 1e30f, d1B = 1e30f, d2B = 1e30f;
  int i0A = 0, i1A = 0, i2A = 0, i0B = 0, i1B = 0, i2B = 0;
  int gbase = q * MQ;

  f32x2 nuxA = { -uxA, -uxA }, nuyA = { -uyA, -uyA }, nuzA = { -uzA, -uzA };
  f32x2 nuxB = { -uxB, -uxB }, nuyB = { -uyB, -uyB }, nuzB = { -uzB, -uzB };

  // Unconditional insert for both queries; chains independent -> interleaved issue.
  // Index updates: exact R4/R8 compare/cndmask logic. d-updates: min+med3
  // (value-identical incl ties — hw-verified via R10 pass-1 / R13 absmax).
#define NN_INS2(ddA, ddB, qq)                                           \
  {                                                                     \
    int jm = gbase + jb + (qq);                                         \
    bool a0 = (ddA) < d0A, a1 = (ddA) < d1A, a2 = (ddA) < d2A;          \
    bool b0 = (ddB) < d0B, b1 = (ddB) < d1B, b2 = (ddB) < d2B;          \
    i2A = a1 ? i1A : (a2 ? jm : i2A);                                   \
    i2B = b1 ? i1B : (b2 ? jm : i2B);                                   \
    i1A = a0 ? i0A : (a1 ? jm : i1A);                                   \
    i1B = b0 ? i0B : (b1 ? jm : i1B);                                   \
    i0A = a0 ? jm : i0A;                                                \
    i0B = b0 ? jm : i0B;                                                \
    float tA1 = med3f(d0A, d1A, (ddA));                                 \
    float tB1 = med3f(d0B, d1B, (ddB));                                 \
    float tA2 = med3f(d1A, d2A, (ddA));                                 \
    float tB2 = med3f(d1B, d2B, (ddB));                                 \
    d0A = fminf(d0A, (ddA)); d1A = tA1; d2A = tA2;                      \
    d0B = fminf(d0B, (ddB)); d1B = tB1; d2B = tB2;                      \
  }

  const f32x2* kx2 = (const f32x2*)kx;
  const f32x2* ky2 = (const f32x2*)ky;
  const f32x2* kz2 = (const f32x2*)kz;
  for (int jb = 0; jb < MQ; jb += 8) {
    int h = jb >> 1;
    f32x2 xa = kx2[h],     ya = ky2[h],     za = kz2[h];
    f32x2 xb = kx2[h + 1], yb = ky2[h + 1], zb = kz2[h + 1];
    f32x2 xc = kx2[h + 2], yc = ky2[h + 2], zc = kz2[h + 2];
    f32x2 xd = kx2[h + 3], yd = ky2[h + 3], zd = kz2[h + 3];
    // dd = (k-u)^2 summed; (k-u)^2 == (u-k)^2 bit-exact in fp32
    f32x2 dxaA = pk_add(xa, nuxA), dyaA = pk_add(ya, nuyA), dzaA = pk_add(za, nuzA);
    f32x2 ddaA = pk_fma(dzaA, dzaA, pk_fma(dyaA, dyaA, pk_mul(dxaA, dxaA)));
    f32x2 dxaB = pk_add(xa, nuxB), dyaB = pk_add(ya, nuyB), dzaB = pk_add(za, nuzB);
    f32x2 ddaB = pk_fma(dzaB, dzaB, pk_fma(dyaB, dyaB, pk_mul(dxaB, dxaB)));
    f32x2 dxbA = pk_add(xb, nuxA), dybA = pk_add(yb, nuyA), dzbA = pk_add(zb, nuzA);
    f32x2 ddbA = pk_fma(dzbA, dzbA, pk_fma(dybA, dybA, pk_mul(dxbA, dxbA)));
    f32x2 dxbB = pk_add(xb, nuxB), dybB = pk_add(yb, nuyB), dzbB = pk_add(zb, nuzB);
    f32x2 ddbB = pk_fma(dzbB, dzbB, pk_fma(dybB, dybB, pk_mul(dxbB, dxbB)));
    f32x2 dxcA = pk_add(xc, nuxA), dycA = pk_add(yc, nuyA), dzcA = pk_add(zc, nuzA);
    f32x2 ddcA = pk_fma(dzcA, dzcA, pk_fma(dycA, dycA, pk_mul(dxcA, dxcA)));
    f32x2 dxcB = pk_add(xc, nuxB), dycB = pk_add(yc, nuyB), dzcB = pk_add(zc, nuzB);
    f32x2 ddcB = pk_fma(dzcB, dzcB, pk_fma(dycB, dycB, pk_mul(dxcB, dxcB)));
    f32x2 dxdA = pk_add(xd, nuxA), dydA = pk_add(yd, nuyA), dzdA = pk_add(zd, nuzA);
    f32x2 dddA = pk_fma(dzdA, dzdA, pk_fma(dydA, dydA, pk_mul(dxdA, dxdA)));
    f32x2 dxdB = pk_add(xd, nuxB), dydB = pk_add(yd, nuyB), dzdB = pk_add(zd, nuzB);
    f32x2 dddB = pk_fma(dzdB, dzdB, pk_fma(dydB, dydB, pk_mul(dxdB, dxdB)));
    NN_INS2(ddaA.x, ddaB.x, 0) NN_INS2(ddaA.y, ddaB.y, 1)
    NN_INS2(ddbA.x, ddbB.x, 2) NN_INS2(ddbA.y, ddbB.y, 3)
    NN_INS2(ddcA.x, ddcB.x, 4) NN_INS2(ddcA.y, ddcB.y, 5)
    NN_INS2(dddA.x, dddB.x, 6) NN_INS2(dddA.y, dddB.y, 7)
  }
#undef NN_INS2

  size_t oA = (((size_t)b * Nn + nA) * NQ + q) * 3;
  pd[oA] = d0A; pd[oA + 1] = d1A; pd[oA + 2] = d2A;
  pi[oA] = i0A; pi[oA + 1] = i1A; pi[oA + 2] = i2A;
  size_t oB = (((size_t)b * Nn + nB) * NQ + q) * 3;
  pd[oB] = d0B; pd[oB + 1] = d1B; pd[oB + 2] = d2B;
  pi[oB] = i0B; pi[oB + 1] = i1B; pi[oB + 2] = i2B;
}

// ------------- fused: 8-way merge -> gather+concat -> MLP1 -> MLP2 -> out -------------
// block = 256 thr (4 waves), 64 cols x 256 rows. grid = 8*128 = 1024.
// R12 (kept): LDS 32KB (6-plane F buffer filled twice + Hs overlay) -> all 4
// blocks/CU resident (was 48KB -> 3/CU, Occ 21.5%, 85us; now <66us).
__global__ __launch_bounds__(256) void fused_gemm_k(
    const float* __restrict__ uf, const short* __restrict__ kfTb,
    const short* __restrict__ W1f, const float* __restrict__ b1,
    const short* __restrict__ W2f, const float* __restrict__ b2,
    const float* __restrict__ pd, const int* __restrict__ pi,
    float* __restrict__ out) {
  __shared__ short Fs[KT2 * 4 * 64 * 8];  // 32KB: Hs region for K2; head 24KB = 6-plane F buf
  short* Hs = Fs;
  int bid = blockIdx.x;
  int b = bid >> 7, bt = bid & 127;  // n0 = bt*64
  int tid = threadIdx.x, lane = tid & 63, wv = tid >> 6;
  int quad = lane >> 4, col = lane & 15;
  const int nq = bt * 64 + wv * 16 + col;  // this thread's point

  // ---- merge: in-register 8-way NN merge (tree of 7 stable merges).
  // Tree order (left = lower q-segment = lower global indices) preserves the
  // sequential-merge tie semantics. Temps t/Jt-prefixed (R10: shadowed C1/C2).
  float w0, w1, w2;
  int g0, g1, g2;
  {
    size_t pbase = (size_t)(b * Nn + nq) * (NQ * 3);  // stride 24 floats (96B), 16B-aligned
    float4 pa = *(const float4*)&pd[pbase];
    float4 pb = *(const float4*)&pd[pbase + 4];
    float4 pc = *(const float4*)&pd[pbase + 8];
    float4 pe = *(const float4*)&pd[pbase + 12];
    float4 pf = *(const float4*)&pd[pbase + 16];
    float4 pg = *(const float4*)&pd[pbase + 20];
    int4 qa = *(const int4*)&pi[pbase];
    int4 qb = *(const int4*)&pi[pbase + 4];
    int4 qc = *(const int4*)&pi[pbase + 8];
    int4 qe = *(const int4*)&pi[pbase + 12];
    int4 qf = *(const int4*)&pi[pbase + 16];
    int4 qg = *(const int4*)&pi[pbase + 20];
    float tA0,tA1,tA2,tB0,tB1,tB2,tC0,tC1,tC2,tD0,tD1,tD2,tE0,tE1,tE2,tF0,tF1,tF2,m0,m1,m2;
    int JA0,JA1,JA2,JB0,JB1,JB2,JC0,JC1,JC2,JD0,JD1,JD2,JE0,JE1,JE2,JF0,JF1,JF2;
    merge3(pa.x, pa.y, pa.z, qa.x, qa.y, qa.z,
           pa.w, pb.x, pb.y, qa.w, qb.x, qb.y, tA0, tA1, tA2, JA0, JA1, JA2);
    merge3(pb.z, pb.w, pc.x, qb.z, qb.w, qc.x,
           pc.y, pc.z, pc.w, qc.y, qc.z, qc.w, tB0, tB1, tB2, JB0, JB1, JB2);
    merge3(pe.x, pe.y, pe.z, qe.x, qe.y, qe.z,
           pe.w, pf.x, pf.y, qe.w, qf.x, qf.y, tC0, tC1, tC2, JC0, JC1, JC2);
    merge3(pf.z, pf.w, pg.x, qf.z, qf.w, qg.x,
           pg.y, pg.z, pg.w, qg.y, qg.z, qg.w, tD0, tD1, tD2, JD0, JD1, JD2);
    merge3(tA0, tA1, tA2, JA0, JA1, JA2, tB0, tB1, tB2, JB0, JB1, JB2,
           tE0, tE1, tE2, JE0, JE1, JE2);
    merge3(tC0, tC1, tC2, JC0, JC1, JC2, tD0, tD1, tD2, JD0, JD1, JD2,
           tF0, tF1, tF2, JF0, JF1, JF2);
    merge3(tE0, tE1, tE2, JE0, JE1, JE2, tF0, tF1, tF2, JF0, JF1, JF2,
           m0, m1, m2, g0, g1, g2);
    float s0 = sqrtf(m0), s1 = sqrtf(m1), s2 = sqrtf(m2);
    float r0 = 1.f / (s0 + 1e-8f), r1 = 1.f / (s1 + 1e-8f), r2 = 1.f / (s2 + 1e-8f);
    float rs = 1.f / (r0 + r1 + r2);
    w0 = r0 * rs; w1 = r1 * rs; w2 = r2 * rs;
  }
  const short* kfb = kfTb + (size_t)b * Mm * C2;

#define GATHER_KT(kt, plane)                                                  \
  {                                                                           \
    int c0 = (kt) * 32 + quad * 8;                                            \
    uint4 q0 = *(const uint4*)&kfb[(size_t)g0 * C2 + c0];                     \
    uint4 q1 = *(const uint4*)&kfb[(size_t)g1 * C2 + c0];                     \
    uint4 q2 = *(const uint4*)&kfb[(size_t)g2 * C2 + c0];                     \
    float e0 = w0 * bflo(q0.x) + w1 * bflo(q1.x) + w2 * bflo(q2.x);           \
    float e1 = w0 * bfhi(q0.x) + w1 * bfhi(q1.x) + w2 * bfhi(q2.x);           \
    float e2 = w0 * bflo(q0.y) + w1 * bflo(q1.y) + w2 * bflo(q2.y);           \
    float e3 = w0 * bfhi(q0.y) + w1 * bfhi(q1.y) + w2 * bfhi(q2.y);           \
    float e4 = w0 * bflo(q0.z) + w1 * bflo(q1.z) + w2 * bflo(q2.z);           \
    float e5 = w0 * bfhi(q0.z) + w1 * bfhi(q1.z) + w2 * bfhi(q2.z);           \
    float e6 = w0 * bflo(q0.w) + w1 * bflo(q1.w) + w2 * bflo(q2.w);           \
    float e7 = w0 * bfhi(q0.w) + w1 * bfhi(q1.w) + w2 * bfhi(q2.w);           \
    uint4 packed;                                                             \
    packed.x = pk2bf(e0, e1); packed.y = pk2bf(e2, e3);                       \
    packed.z = pk2bf(e4, e5); packed.w = pk2bf(e6, e7);                       \
    *(uint4*)&Fs[(((plane) * 4 + wv) * 64 + lane) * 8] = packed;              \
  }

  // ---- Phase A-1: gather kt 0..5 into planes 0..5
#pragma unroll 3
  for (int kt = 0; kt < 6; ++kt) GATHER_KT(kt, kt)
  __syncthreads();  // B1: F half 1 ready

  // ---- K1a: kt 0..5
  f32x4 acc[4][4];
#pragma unroll
  for (int r = 0; r < 4; ++r)
#pragma unroll
    for (int c = 0; c < 4; ++c) acc[r][c] = (f32x4){0.f, 0.f, 0.f, 0.f};

  for (int kt = 0; kt < 6; ++kt) {
    bf16x8 Afr[4], Bfr[4];
#pragma unroll
    for (int r = 0; r < 4; ++r)
      Afr[r] = *(const bf16x8*)(W1f + ((size_t)(kt * RT + wv * 4 + r) * 64 + lane) * 8);
#pragma unroll
    for (int c = 0; c < 4; ++c)
      Bfr[c] = *(const bf16x8*)&Fs[((kt * 4 + c) * 64 + lane) * 8];
#pragma unroll
    for (int r = 0; r < 4; ++r)
#pragma unroll
      for (int c = 0; c < 4; ++c)
        acc[r][c] = __builtin_amdgcn_mfma_f32_16x16x32_bf16(Afr[r], Bfr[c], acc[r][c], 0, 0, 0);
  }
  __syncthreads();  // B2: half-1 reads done; planes reusable

  // ---- Phase A-2: gather kt 6..7, uf kt 8..11 into planes 0..5
  GATHER_KT(6, 0)
  GATHER_KT(7, 1)
#pragma unroll 2
  for (int kt = 8; kt < 12; ++kt) {  // unknow_feats region (C1 channels)
    int c1 = (kt - 8) * 32 + quad * 8;
    float e[8];
#pragma unroll
    for (int j = 0; j < 8; ++j)
      e[j] = uf[((size_t)b * C1 + c1 + j) * Nn + nq];
    uint4 packed;
    packed.x = pk2bf(e[0], e[1]); packed.y = pk2bf(e[2], e[3]);
    packed.z = pk2bf(e[4], e[5]); packed.w = pk2bf(e[6], e[7]);
    *(uint4*)&Fs[(((kt - 6) * 4 + wv) * 64 + lane) * 8] = packed;
  }
#undef GATHER_KT
  __syncthreads();  // B3: F half 2 ready

  // ---- K1b: kt 6..11 reading plane kt-6
  for (int kt = 6; kt < KT1; ++kt) {
    bf16x8 Afr[4], Bfr[4];
#pragma unroll
    for (int r = 0; r < 4; ++r)
      Afr[r] = *(const bf16x8*)(W1f + ((size_t)(kt * RT + wv * 4 + r) * 64 + lane) * 8);
#pragma unroll
    for (int c = 0; c < 4; ++c)
      Bfr[c] = *(const bf16x8*)&Fs[(((kt - 6) * 4 + c) * 64 + lane) * 8];
#pragma unroll
    for (int r = 0; r < 4; ++r)
#pragma unroll
      for (int c = 0; c < 4; ++c)
        acc[r][c] = __builtin_amdgcn_mfma_f32_16x16x32_bf16(Afr[r], Bfr[c], acc[r][c], 0, 0, 0);
  }

  // ---- Epilogue 1: bias+relu in D-layout (regs only), then barrier, then
  // register bpermute D->B-frag into Hs.
#pragma unroll
  for (int r = 0; r < 4; ++r) {
    f32x4 bq = *(const f32x4*)&b1[wv * 64 + r * 16 + quad * 4];
#pragma unroll
    for (int c = 0; c < 4; ++c)
#pragma unroll
      for (int reg = 0; reg < 4; ++reg)
        acc[r][c][reg] = fmaxf(acc[r][c][reg] + bq[reg], 0.f);
  }
  __syncthreads();  // B4: K1b's Fs reads done; Hs (overlapping region) may be written
  {
    int addr_lo = (((quad & 1) * 2) * 16 + col) * 4;  // src lane*4 for j<4
    bool hiSel = lane >= 32;
#pragma unroll
    for (int ktl = 0; ktl < 2; ++ktl)
#pragma unroll
      for (int c = 0; c < 4; ++c) {
        float e[8];
#pragma unroll
        for (int j = 0; j < 8; ++j) {
          int addr = addr_lo + (j >> 2) * 64;
          int lo = __builtin_amdgcn_ds_bpermute(addr, __float_as_int(acc[ktl * 2][c][j & 3]));
          int hi = __builtin_amdgcn_ds_bpermute(addr, __float_as_int(acc[ktl * 2 + 1][c][j & 3]));
          e[j] = __int_as_float(hiSel ? hi : lo);
        }
        uint4 packed;
        packed.x = pk2bf(e[0], e[1]); packed.y = pk2bf(e[2], e[3]);
        packed.z = pk2bf(e[4], e[5]); packed.w = pk2bf(e[6], e[7]);
        *(uint4*)&Hs[(((wv * 2 + ktl) * 4 + c) * 64 + lane) * 8] = packed;
      }
  }
  __syncthreads();  // B5: Hs ready

  // ---- K-loop 2
  f32x4 acc2[4][4];
#pragma unroll
  for (int r = 0; r < 4; ++r)
#pragma unroll
    for (int c = 0; c < 4; ++c) acc2[r][c] = (f32x4){0.f, 0.f, 0.f, 0.f};

  for (int kt = 0; kt < KT2; ++kt) {
    bf16x8 Afr[4], Bfr[4];
#pragma unroll
    for (int r = 0; r < 4; ++r)
      Afr[r] = *(const bf16x8*)(W2f + ((size_t)(kt * RT + wv * 4 + r) * 64 + lane) * 8);
#pragma unroll
    for (int c = 0; c < 4; ++c)
      Bfr[c] = *(const bf16x8*)&Hs[((kt * 4 + c) * 64 + lane) * 8];
#pragma unroll
    for (int r = 0; r < 4; ++r)
#pragma unroll
      for (int c = 0; c < 4; ++c)
        acc2[r][c] = __builtin_amdgcn_mfma_f32_16x16x32_bf16(Afr[r], Bfr[c], acc2[r][c], 0, 0, 0);
  }

  // ---- Epilogue 2: bias+relu, store
#pragma unroll
  for (int r = 0; r < 4; ++r) {
    f32x4 bq = *(const f32x4*)&b2[wv * 64 + r * 16 + quad * 4];
#pragma unroll
    for (int c = 0; c < 4; ++c)
#pragma unroll
      for (int reg = 0; reg < 4; ++reg) {
        int rowg = wv * 64 + r * 16 + quad * 4 + reg;
        int n = bt * 64 + c * 16 + col;
        out[((size_t)b * Hh + rowg) * Nn + n] = fmaxf(acc2[r][c][reg] + bq[reg], 0.f);
      }
  }
}

extern "C" void kernel_launch(void* const* d_in, const int* in_sizes, int n_in,
                              void* d_out, int out_size, void* d_ws, size_t ws_size,
                              hipStream_t stream) {
  const float* unknown = (const float*)d_in[0];
  const float* known   = (const float*)d_in[1];
  const float* uf      = (const float*)d_in[2];
  const float* kf      = (const float*)d_in[3];
  const float* W1      = (const float*)d_in[4];
  const float* b1      = (const float*)d_in[5];
  const float* W2      = (const float*)d_in[6];
  const float* b2      = (const float*)d_in[7];
  float* out = (float*)d_out;

  // ws layout (~21.5 MB)
  char* p = (char*)d_ws;
  short* kfTb = (short*)p; p += (size_t)Bb * Mm * C2 * 2;   // 8.4 MB bf16
  short* W1f = (short*)p;  p += (size_t)KT1 * RT * 64 * 8 * 2;
  short* W2f = (short*)p;  p += (size_t)KT2 * RT * 64 * 8 * 2;
  float* pd  = (float*)p;  p += (size_t)Bb * Nn * NQ * 3 * 4;  // 6.3 MB
  int* pi    = (int*)p;    p += (size_t)Bb * Nn * NQ * 3 * 4;  // 6.3 MB

  const int prep_blocks = 4096 + (KT1 * RT * 64 + KT2 * RT * 64 + 255) / 256;
  prep_all_k<<<dim3(prep_blocks), dim3(256), 0, stream>>>(kf, kfTb, W1, W2, W1f, W2f);
  nn_part_k<<<dim3(Bb * 16 * NQ), dim3(256), 0, stream>>>(unknown, known, pd, pi);
  fused_gemm_k<<<dim3(Bb * (Nn / 64)), dim3(256), 0, stream>>>(
      uf, kfTb, W1f, b1, W2f, b2, pd, pi, out);
}

// Round 15
// 216.824 us; speedup vs baseline: 1.0245x; 1.0245x over previous
//
#include <hip/hip_runtime.h>

using bf16x8 = __attribute__((ext_vector_type(8))) short;
using f32x4  = __attribute__((ext_vector_type(4))) float;
using f32x2  = __attribute__((ext_vector_type(2))) float;

constexpr int Bb = 8, Nn = 8192, Mm = 2048, C1 = 128, C2 = 256, Hh = 256, K1 = 384;
constexpr int KT1 = K1 / 32;   // 12 k-tiles for GEMM1
constexpr int KT2 = Hh / 32;   // 8 k-tiles for GEMM2
constexpr int RT = Hh / 16;    // 16 row-tiles
constexpr int NQ = 4;          // R15: back to 4. Measured nn ladder: NQ=4 gated = 64.0us
                               // (best of 6 variants); NQ=8 variants 66.5-70.5us (gate
                               // fires 96% at MQ=256 -> more chain work than occupancy buys).
constexpr int MQ = Mm / NQ;    // 512 candidates per quarter

__device__ __forceinline__ short f2bf(float x) {  // RNE float->bf16
  union { float f; unsigned u; } v; v.f = x;
  unsigned r = v.u + 0x7fff + ((v.u >> 16) & 1);
  return (short)(r >> 16);
}

// packed RNE float2 -> 2x bf16 in one dword (hw instr when available)
__device__ __forceinline__ unsigned pk2bf(float a, float b) {
#if defined(__has_builtin) && __has_builtin(__builtin_amdgcn_cvt_pk_bf16_f32)
  typedef __attribute__((ext_vector_type(2))) __bf16 bf2_t;
  bf2_t r = __builtin_amdgcn_cvt_pk_bf16_f32(a, b);
  union { bf2_t v; unsigned u; } cvt; cvt.v = r;
  return cvt.u;
#else
  return (unsigned)(unsigned short)f2bf(a) | ((unsigned)(unsigned short)f2bf(b) << 16);
#endif
}

// unpack a dword holding 2 bf16 (lo = element 2i, hi = element 2i+1)
__device__ __forceinline__ float bflo(unsigned d) { return __uint_as_float(d << 16); }
__device__ __forceinline__ float bfhi(unsigned d) { return __uint_as_float(d & 0xffff0000u); }

// packed fp32 (CDNA3+). Lessons: feed ONLY from direct f32x2 loads (R9);
// two-pass recompute loses (R10); v_pk fp32 is throughput-neutral vs scalar
// (R13); 2-queries/thread loses TLP (R14). NQ=4 gated one-pass is the floor.
__device__ __forceinline__ f32x2 pk_add(f32x2 a, f32x2 b) {
  f32x2 d; asm("v_pk_add_f32 %0, %1, %2" : "=v"(d) : "v"(a), "v"(b)); return d;
}
__device__ __forceinline__ f32x2 pk_mul(f32x2 a, f32x2 b) {
  f32x2 d; asm("v_pk_mul_f32 %0, %1, %2" : "=v"(d) : "v"(a), "v"(b)); return d;
}
__device__ __forceinline__ f32x2 pk_fma(f32x2 a, f32x2 b, f32x2 c) {
  f32x2 d; asm("v_pk_fma_f32 %0, %1, %2, %3" : "=v"(d) : "v"(a), "v"(b), "v"(c)); return d;
}

// stable 2-list merge of sorted triples; ties prefer list a (lower global idx)
__device__ __forceinline__ void merge3(float a0, float a1, float a2, int A0, int A1, int A2,
                                       float b0, float b1, float b2, int B0, int B1, int B2,
                                       float& m0, float& m1, float& m2,
                                       int& j0, int& j1, int& j2) {
  bool ta = a0 <= b0;
  m0 = ta ? a0 : b0; j0 = ta ? A0 : B0;
  float na0 = ta ? a1 : a0, na1 = ta ? a2 : a1;
  int   nA0 = ta ? A1 : A0, nA1 = ta ? A2 : A1;
  float nb0 = ta ? b0 : b1, nb1 = ta ? b1 : b2;
  int   nB0 = ta ? B0 : B1, nB1 = ta ? B1 : B2;
  ta = na0 <= nb0;
  m1 = ta ? na0 : nb0; j1 = ta ? nA0 : nB0;
  float ma0 = ta ? na1 : na0; int mA0 = ta ? nA1 : nA0;
  float mb0 = ta ? nb0 : nb1; int mB0 = ta ? nB0 : nB1;
  ta = ma0 <= mb0;
  m2 = ta ? ma0 : mb0; j2 = ta ? mA0 : mB0;
}

// ------------- prep: kf transpose->bf16 (blocks 0..4095) + W frag prep -------------
// NOTE: prep, nn, fused stay SEPARATE kernels (R5/R6: fusing roles into one grid
// serialized the nn phase behind the transpose blocks, +40 us; launch overhead is
// fixed ~85 us regardless of kernel count — do not re-fuse).
__global__ __launch_bounds__(256) void prep_all_k(const float* __restrict__ kf,
                                                  short* __restrict__ kfTb,
                                                  const float* __restrict__ W1,
                                                  const float* __restrict__ W2,
                                                  short* __restrict__ W1f,
                                                  short* __restrict__ W2f) {
  __shared__ float tile[32][33];
  int bid = blockIdx.x, tid = threadIdx.x;
  if (bid < 4096) {  // transpose role: (B,C2,Mm) f32 -> (B,Mm,C2) bf16
    int cx = bid & 63, ry = (bid >> 6) & 7, z = bid >> 9;
    const float* src = kf + (size_t)z * C2 * Mm;
    short* dst = kfTb + (size_t)z * Mm * C2;
    int c0 = cx * 32, r0 = ry * 32;  // c0: point base, r0: channel base
    int tx = tid & 31, ty = tid >> 5;
#pragma unroll
    for (int rr = ty; rr < 32; rr += 8)
      tile[rr][tx] = src[(size_t)(r0 + rr) * Mm + c0 + tx];
    __syncthreads();
#pragma unroll
    for (int cc = ty; cc < 32; cc += 8)
      dst[(size_t)(c0 + cc) * C2 + r0 + tx] = f2bf(tile[tx][cc]);
    return;
  }
  // W-prep role: A-frag planes (lane holds A[m=lane&15][k0..k0+7], k0=(lane>>4)*8)
  int id = (bid - 4096) * 256 + tid;
  const int n1 = KT1 * RT * 64;
  const int n2 = KT2 * RT * 64;
  if (id < n1) {
    int lane = id & 63, t = id >> 6;
    int kt = t / RT, rt = t % RT;
    int m = rt * 16 + (lane & 15), k0 = kt * 32 + (lane >> 4) * 8;
    bf16x8 f;
#pragma unroll
    for (int j = 0; j < 8; ++j) f[j] = f2bf(W1[(size_t)m * K1 + k0 + j]);
    *(bf16x8*)(W1f + (size_t)id * 8) = f;
  } else if (id < n1 + n2) {
    int id2 = id - n1;
    int lane = id2 & 63, t = id2 >> 6;
    int kt = t / RT, rt = t % RT;
    int m = rt * 16 + (lane & 15), k0 = kt * 32 + (lane >> 4) * 8;
    bf16x8 f;
#pragma unroll
    for (int j = 0; j < 8; ++j) f[j] = f2bf(W2[(size_t)m * Hh + k0 + j]);
    *(bf16x8*)(W2f + (size_t)id2 * 8) = f;
  }
}

// ------------- three_nn over a quarter of the candidate set (R8-verbatim) -------------
// grid: b(8) x nblk(32) x q(4) = 1024 blocks of 256 -> 16 waves/CU (4/SIMD).
// Measured 64.0us (R8) — best of 6 variants (gated cndmask chain, pk distances,
// 4-wide). Gate fires ~74% at MQ=512; VALUBusy 66%, VGPR 16. Do not re-tune.
__global__ __launch_bounds__(256) void nn_quarter_k(const float* __restrict__ unknown,
                                                    const float* __restrict__ known,
                                                    float* __restrict__ pd,
                                                    int* __restrict__ pi) {
  __shared__ float kx[MQ], ky[MQ], kz[MQ];
  int bid = blockIdx.x;
  int b = bid >> 7, rem = bid & 127;
  int q = rem & 3, nblk = rem >> 2;
  int n = nblk * 256 + threadIdx.x;
  const float* kb = known + ((size_t)b * Mm + q * MQ) * 3;
  for (int p = threadIdx.x; p < MQ; p += 256) {
    kx[p] = kb[3 * p]; ky[p] = kb[3 * p + 1]; kz[p] = kb[3 * p + 2];
  }
  __syncthreads();

  size_t ui = ((size_t)b * Nn + n) * 3;
  float ux = unknown[ui], uy = unknown[ui + 1], uz = unknown[ui + 2];
  float d0 = 1e30f, d1 = 1e30f, d2 = 1e30f;
  int i0 = 0, i1 = 0, i2 = 0;
  int gbase = q * MQ;

  // broadcast negated query into packed pairs (once per thread)
  f32x2 nux = { -ux, -ux }, nuy = { -uy, -uy }, nuz = { -uz, -uz };

#define NN_INS(dd, qq)                                                  \
  {                                                                     \
    if (__any((dd) < d2)) { /* wave-uniform skip of the insert chain */ \
      int jm = gbase + jb + (qq);                                       \
      bool c0 = (dd) < d0, c1 = (dd) < d1, c2 = (dd) < d2;              \
      d2 = c1 ? d1 : (c2 ? (dd) : d2); i2 = c1 ? i1 : (c2 ? jm : i2);   \
      d1 = c0 ? d0 : (c1 ? (dd) : d1); i1 = c0 ? i0 : (c1 ? jm : i1);   \
      d0 = c0 ? (dd) : d0;             i0 = c0 ? jm : i0;               \
    }                                                                   \
  }

  const f32x2* kx2 = (const f32x2*)kx;
  const f32x2* ky2 = (const f32x2*)ky;
  const f32x2* kz2 = (const f32x2*)kz;
  for (int jb = 0; jb < MQ; jb += 4) {
    int h = jb >> 1;
    f32x2 xa = kx2[h], xb = kx2[h + 1];
    f32x2 ya = ky2[h], yb = ky2[h + 1];
    f32x2 za = kz2[h], zb = kz2[h + 1];
    // dd = (k-u)^2 summed; (k-u)^2 == (u-k)^2 bit-exact in fp32
    f32x2 dxa = pk_add(xa, nux), dya = pk_add(ya, nuy), dza = pk_add(za, nuz);
    f32x2 dda = pk_fma(dza, dza, pk_fma(dya, dya, pk_mul(dxa, dxa)));
    f32x2 dxb = pk_add(xb, nux), dyb = pk_add(yb, nuy), dzb = pk_add(zb, nuz);
    f32x2 ddb = pk_fma(dzb, dzb, pk_fma(dyb, dyb, pk_mul(dxb, dxb)));
    NN_INS(dda.x, 0)
    NN_INS(dda.y, 1)
    NN_INS(ddb.x, 2)
    NN_INS(ddb.y, 3)
  }
#undef NN_INS

  size_t o = (((size_t)b * Nn + n) * NQ + q) * 3;
  pd[o] = d0; pd[o + 1] = d1; pd[o + 2] = d2;
  pi[o] = i0; pi[o + 1] = i1; pi[o + 2] = i2;
}

// ------------- fused: 4-way merge -> gather+concat -> MLP1 -> MLP2 -> out -------------
// block = 256 thr (4 waves), 64 cols x 256 rows. grid = 8*128 = 1024.
// R12 (kept): LDS 32KB — 6-plane F buffer filled twice (A1: kt0-5 -> K1a ->
// A2: kt6-11 -> K1b) + Hs overlay for K2 -> all 4 blocks/CU resident
// (48KB capped at 3/CU: Occ 21.5%, 85us -> ~60us at 32KB).
// R15: phase-A head back to the NQ=4 3-merge tree (R8's code).
__global__ __launch_bounds__(256) void fused_gemm_k(
    const float* __restrict__ uf, const short* __restrict__ kfTb,
    const short* __restrict__ W1f, const float* __restrict__ b1,
    const short* __restrict__ W2f, const float* __restrict__ b2,
    const float* __restrict__ pd, const int* __restrict__ pi,
    float* __restrict__ out) {
  __shared__ short Fs[KT2 * 4 * 64 * 8];  // 32KB: Hs region for K2; head 24KB = 6-plane F buf
  short* Hs = Fs;
  int bid = blockIdx.x;
  int b = bid >> 7, bt = bid & 127;  // n0 = bt*64
  int tid = threadIdx.x, lane = tid & 63, wv = tid >> 6;
  int quad = lane >> 4, col = lane & 15;
  const int nq = bt * 64 + wv * 16 + col;  // this thread's point

  // ---- merge: in-register 4-way NN merge (tree of 3 stable merges, R8 code).
  // Temps t-prefixed (R10 lesson: unprefixed names shadowed constexpr C1/C2).
  float w0, w1, w2;
  int g0, g1, g2;
  {
    size_t pbase = (size_t)(b * Nn + nq) * (NQ * 3);  // stride 12 floats (48B), 16B-aligned
    float4 da = *(const float4*)&pd[pbase];
    float4 db = *(const float4*)&pd[pbase + 4];
    float4 dc = *(const float4*)&pd[pbase + 8];
    int4 ia = *(const int4*)&pi[pbase];
    int4 ib = *(const int4*)&pi[pbase + 4];
    int4 ic = *(const int4*)&pi[pbase + 8];
    float t0, t1, t2, u0, u1, u2, m0, m1, m2;
    int T0, T1, T2, U0, U1, U2;
    merge3(da.x, da.y, da.z, ia.x, ia.y, ia.z,
           da.w, db.x, db.y, ia.w, ib.x, ib.y, t0, t1, t2, T0, T1, T2);
    merge3(db.z, db.w, dc.x, ib.z, ib.w, ic.x,
           dc.y, dc.z, dc.w, ic.y, ic.z, ic.w, u0, u1, u2, U0, U1, U2);
    merge3(t0, t1, t2, T0, T1, T2, u0, u1, u2, U0, U1, U2,
           m0, m1, m2, g0, g1, g2);
    float s0 = sqrtf(m0), s1 = sqrtf(m1), s2 = sqrtf(m2);
    float r0 = 1.f / (s0 + 1e-8f), r1 = 1.f / (s1 + 1e-8f), r2 = 1.f / (s2 + 1e-8f);
    float rs = 1.f / (r0 + r1 + r2);
    w0 = r0 * rs; w1 = r1 * rs; w2 = r2 * rs;
  }
  const short* kfb = kfTb + (size_t)b * Mm * C2;

#define GATHER_KT(kt, plane)                                                  \
  {                                                                           \
    int c0 = (kt) * 32 + quad * 8;                                            \
    uint4 q0 = *(const uint4*)&kfb[(size_t)g0 * C2 + c0];                     \
    uint4 q1 = *(const uint4*)&kfb[(size_t)g1 * C2 + c0];                     \
    uint4 q2 = *(const uint4*)&kfb[(size_t)g2 * C2 + c0];                     \
    float e0 = w0 * bflo(q0.x) + w1 * bflo(q1.x) + w2 * bflo(q2.x);           \
    float e1 = w0 * bfhi(q0.x) + w1 * bfhi(q1.x) + w2 * bfhi(q2.x);           \
    float e2 = w0 * bflo(q0.y) + w1 * bflo(q1.y) + w2 * bflo(q2.y);           \
    float e3 = w0 * bfhi(q0.y) + w1 * bfhi(q1.y) + w2 * bfhi(q2.y);           \
    float e4 = w0 * bflo(q0.z) + w1 * bflo(q1.z) + w2 * bflo(q2.z);           \
    float e5 = w0 * bfhi(q0.z) + w1 * bfhi(q1.z) + w2 * bfhi(q2.z);           \
    float e6 = w0 * bflo(q0.w) + w1 * bflo(q1.w) + w2 * bflo(q2.w);           \
    float e7 = w0 * bfhi(q0.w) + w1 * bfhi(q1.w) + w2 * bfhi(q2.w);           \
    uint4 packed;                                                             \
    packed.x = pk2bf(e0, e1); packed.y = pk2bf(e2, e3);                       \
    packed.z = pk2bf(e4, e5); packed.w = pk2bf(e6, e7);                       \
    *(uint4*)&Fs[(((plane) * 4 + wv) * 64 + lane) * 8] = packed;              \
  }

  // ---- Phase A-1: gather kt 0..5 into planes 0..5
#pragma unroll 3
  for (int kt = 0; kt < 6; ++kt) GATHER_KT(kt, kt)
  __syncthreads();  // B1: F half 1 ready

  // ---- K1a: kt 0..5
  f32x4 acc[4][4];
#pragma unroll
  for (int r = 0; r < 4; ++r)
#pragma unroll
    for (int c = 0; c < 4; ++c) acc[r][c] = (f32x4){0.f, 0.f, 0.f, 0.f};

  for (int kt = 0; kt < 6; ++kt) {
    bf16x8 Afr[4], Bfr[4];
#pragma unroll
    for (int r = 0; r < 4; ++r)
      Afr[r] = *(const bf16x8*)(W1f + ((size_t)(kt * RT + wv * 4 + r) * 64 + lane) * 8);
#pragma unroll
    for (int c = 0; c < 4; ++c)
      Bfr[c] = *(const bf16x8*)&Fs[((kt * 4 + c) * 64 + lane) * 8];
#pragma unroll
    for (int r = 0; r < 4; ++r)
#pragma unroll
      for (int c = 0; c < 4; ++c)
        acc[r][c] = __builtin_amdgcn_mfma_f32_16x16x32_bf16(Afr[r], Bfr[c], acc[r][c], 0, 0, 0);
  }
  __syncthreads();  // B2: half-1 reads done; planes reusable

  // ---- Phase A-2: gather kt 6..7, uf kt 8..11 into planes 0..5
  GATHER_KT(6, 0)
  GATHER_KT(7, 1)
#pragma unroll 2
  for (int kt = 8; kt < 12; ++kt) {  // unknow_feats region (C1 channels)
    int c1 = (kt - 8) * 32 + quad * 8;
    float e[8];
#pragma unroll
    for (int j = 0; j < 8; ++j)
      e[j] = uf[((size_t)b * C1 + c1 + j) * Nn + nq];
    uint4 packed;
    packed.x = pk2bf(e[0], e[1]); packed.y = pk2bf(e[2], e[3]);
    packed.z = pk2bf(e[4], e[5]); packed.w = pk2bf(e[6], e[7]);
    *(uint4*)&Fs[(((kt - 6) * 4 + wv) * 64 + lane) * 8] = packed;
  }
#undef GATHER_KT
  __syncthreads();  // B3: F half 2 ready

  // ---- K1b: kt 6..11 reading plane kt-6
  for (int kt = 6; kt < KT1; ++kt) {
    bf16x8 Afr[4], Bfr[4];
#pragma unroll
    for (int r = 0; r < 4; ++r)
      Afr[r] = *(const bf16x8*)(W1f + ((size_t)(kt * RT + wv * 4 + r) * 64 + lane) * 8);
#pragma unroll
    for (int c = 0; c < 4; ++c)
      Bfr[c] = *(const bf16x8*)&Fs[(((kt - 6) * 4 + c) * 64 + lane) * 8];
#pragma unroll
    for (int r = 0; r < 4; ++r)
#pragma unroll
      for (int c = 0; c < 4; ++c)
        acc[r][c] = __builtin_amdgcn_mfma_f32_16x16x32_bf16(Afr[r], Bfr[c], acc[r][c], 0, 0, 0);
  }

  // ---- Epilogue 1: bias+relu in D-layout (regs only), then barrier, then
  // register bpermute D->B-frag into Hs.
#pragma unroll
  for (int r = 0; r < 4; ++r) {
    f32x4 bq = *(const f32x4*)&b1[wv * 64 + r * 16 + quad * 4];
#pragma unroll
    for (int c = 0; c < 4; ++c)
#pragma unroll
      for (int reg = 0; reg < 4; ++reg)
        acc[r][c][reg] = fmaxf(acc[r][c][reg] + bq[reg], 0.f);
  }
  __syncthreads();  // B4: K1b's Fs reads done; Hs (overlapping region) may be written
  {
    int addr_lo = (((quad & 1) * 2) * 16 + col) * 4;  // src lane*4 for j<4
    bool hiSel = lane >= 32;
#pragma unroll
    for (int ktl = 0; ktl < 2; ++ktl)
#pragma unroll
      for (int c = 0; c < 4; ++c) {
        float e[8];
#pragma unroll
        for (int j = 0; j < 8; ++j) {
          int addr = addr_lo + (j >> 2) * 64;
          int lo = __builtin_amdgcn_ds_bpermute(addr, __float_as_int(acc[ktl * 2][c][j & 3]));
          int hi = __builtin_amdgcn_ds_bpermute(addr, __float_as_int(acc[ktl * 2 + 1][c][j & 3]));
          e[j] = __int_as_float(hiSel ? hi : lo);
        }
        uint4 packed;
        packed.x = pk2bf(e[0], e[1]); packed.y = pk2bf(e[2], e[3]);
        packed.z = pk2bf(e[4], e[5]); packed.w = pk2bf(e[6], e[7]);
        *(uint4*)&Hs[(((wv * 2 + ktl) * 4 + c) * 64 + lane) * 8] = packed;
      }
  }
  __syncthreads();  // B5: Hs ready

  // ---- K-loop 2
  f32x4 acc2[4][4];
#pragma unroll
  for (int r = 0; r < 4; ++r)
#pragma unroll
    for (int c = 0; c < 4; ++c) acc2[r][c] = (f32x4){0.f, 0.f, 0.f, 0.f};

  for (int kt = 0; kt < KT2; ++kt) {
    bf16x8 Afr[4], Bfr[4];
#pragma unroll
    for (int r = 0; r < 4; ++r)
      Afr[r] = *(const bf16x8*)(W2f + ((size_t)(kt * RT + wv * 4 + r) * 64 + lane) * 8);
#pragma unroll
    for (int c = 0; c < 4; ++c)
      Bfr[c] = *(const bf16x8*)&Hs[((kt * 4 + c) * 64 + lane) * 8];
#pragma unroll
    for (int r = 0; r < 4; ++r)
#pragma unroll
      for (int c = 0; c < 4; ++c)
        acc2[r][c] = __builtin_amdgcn_mfma_f32_16x16x32_bf16(Afr[r], Bfr[c], acc2[r][c], 0, 0, 0);
  }

  // ---- Epilogue 2: bias+relu, store
#pragma unroll
  for (int r = 0; r < 4; ++r) {
    f32x4 bq = *(const f32x4*)&b2[wv * 64 + r * 16 + quad * 4];
#pragma unroll
    for (int c = 0; c < 4; ++c)
#pragma unroll
      for (int reg = 0; reg < 4; ++reg) {
        int rowg = wv * 64 + r * 16 + quad * 4 + reg;
        int n = bt * 64 + c * 16 + col;
        out[((size_t)b * Hh + rowg) * Nn + n] = fmaxf(acc2[r][c][reg] + bq[reg], 0.f);
      }
  }
}

extern "C" void kernel_launch(void* const* d_in, const int* in_sizes, int n_in,
                              void* d_out, int out_size, void* d_ws, size_t ws_size,
                              hipStream_t stream) {
  const float* unknown = (const float*)d_in[0];
  const float* known   = (const float*)d_in[1];
  const float* uf      = (const float*)d_in[2];
  const float* kf      = (const float*)d_in[3];
  const float* W1      = (const float*)d_in[4];
  const float* b1      = (const float*)d_in[5];
  const float* W2      = (const float*)d_in[6];
  const float* b2      = (const float*)d_in[7];
  float* out = (float*)d_out;

  // ws layout (~16 MB)
  char* p = (char*)d_ws;
  short* kfTb = (short*)p; p += (size_t)Bb * Mm * C2 * 2;   // 8.4 MB bf16
  short* W1f = (short*)p;  p += (size_t)KT1 * RT * 64 * 8 * 2;
  short* W2f = (short*)p;  p += (size_t)KT2 * RT * 64 * 8 * 2;
  float* pd  = (float*)p;  p += (size_t)Bb * Nn * NQ * 3 * 4;  // 3.1 MB
  int* pi    = (int*)p;    p += (size_t)Bb * Nn * NQ * 3 * 4;  // 3.1 MB

  const int prep_blocks = 4096 + (KT1 * RT * 64 + KT2 * RT * 64 + 255) / 256;
  prep_all_k<<<dim3(prep_blocks), dim3(256), 0, stream>>>(kf, kfTb, W1, W2, W1f, W2f);
  nn_quarter_k<<<dim3(Bb * 32 * NQ), dim3(256), 0, stream>>>(unknown, known, pd, pi);
  fused_gemm_k<<<dim3(Bb * (Nn / 64)), dim3(256), 0, stream>>>(
      uf, kfTb, W1f, b1, W2f, b2, pd, pi, out);
}